// Round 8
// baseline (169.562 us; speedup 1.0000x reference)
//
#include <hip/hip_runtime.h>
#include <hip/hip_bf16.h>

// ============================================================================
// indices ∈ [0,64) => backbone + theta have only 64 distinct rows. Compute
// per-class (7 MB, L2-resident), bucket batches by class, run only the tiny
// per-batch MLPs with class-shared weights.
// R8: func v8 — v5/v6/v7 all pinned at ~41us: barrier-phased weight staging
// keeps all co-resident waves in the same phase (one pipe busy at a time,
// 2 blocks/CU). v8 reads weights DIRECTLY from global (L2/L3-resident theta,
// coalesced + deduped per wave), LDS only for activation transposes (17KB).
// NSLICE=16 -> 1024 blocks -> 4 blocks/CU x 4 waves = 16 waves/CU of
// de-phased blocks so VALU/LDS/VMEM overlap. 7 barriers/pass, no staging.
// ============================================================================

#define LEAKY 0.2f
#define NCLS 64
#define B_TOT 8192
#define NSLICE 16
#define SESTR 18   // sE row stride (floats)
#define SFSTR 10   // sF/sG row stride (floats)

// theta_e (per class, 5456 fl): W1e[0,128) b1e[128,192) W2e[192,4288)
//   b2e[4288,4352) W3e[4352,5376) b3e[5376,5392)
// theta_f (per class, 21768 fl): W1f[0,4096) b1f[4096,4224) W2f[4224,20608)
//   b2f[20608,20736) W3f[20736,21760) b3f[21760,21768)

__device__ __forceinline__ float lrelu(float x) { return x >= 0.f ? x : LEAKY * x; }

// ---------------------------------------------------------------------------
// K1: blocks 0..63: fused backbone for class c. block 64: bucket. 1024 thr.
// ---------------------------------------------------------------------------
__global__ __launch_bounds__(1024) void backbone_bucket_kernel(
    const float* __restrict__ maps,
    const float* __restrict__ fc1_w, const float* __restrict__ fc1_b,
    const float* __restrict__ fc2_w, const float* __restrict__ fc2_b,
    const float* __restrict__ fc3_w, const float* __restrict__ fc3_b,
    const float* __restrict__ bn_w,  const float* __restrict__ bn_b,
    float* __restrict__ z,
    const int* __restrict__ idx, int* __restrict__ counts,
    int* __restrict__ offsets, int* __restrict__ perm)
{
    __shared__ float m[1024];
    __shared__ __align__(16) float4 red4[1024];
    __shared__ __align__(16) float h1[256];
    __shared__ __align__(16) float h2[128];
    __shared__ __align__(16) float h3[128];
    __shared__ int cnt[16][64];
    __shared__ int wcur[16][64];

    const int t = threadIdx.x;

    if (blockIdx.x == 64) {
        const int w = t >> 6;
        cnt[w][t & 63] = 0;
        __syncthreads();
        int my[8];
#pragma unroll
        for (int r = 0; r < 8; ++r) {
            my[r] = idx[r * 1024 + t];
            atomicAdd(&cnt[w][my[r]], 1);
        }
        __syncthreads();
        if (t < 64) {
            int run = 0;
#pragma unroll
            for (int w2 = 0; w2 < 16; ++w2) {
                const int v = cnt[w2][t];
                wcur[w2][t] = run;
                run += v;
            }
            counts[t] = run;
            int x = run;
            for (int d = 1; d < 64; d <<= 1) {
                const int y = __shfl_up(x, d, 64);
                if (t >= d) x += y;
            }
            const int basec = x - run;
            offsets[t] = basec;
#pragma unroll
            for (int w2 = 0; w2 < 16; ++w2) wcur[w2][t] += basec;
        }
        __syncthreads();
#pragma unroll
        for (int r = 0; r < 8; ++r) {
            const int p = atomicAdd(&wcur[w][my[r]], 1);
            perm[p] = r * 1024 + t;
        }
        return;
    }

    const int c = blockIdx.x;
    m[t] = maps[(size_t)c * 1024 + t];
    __syncthreads();

    // fc1: 1024 -> 256 (leaky)
    {
        const int og = t & 63, ks = t >> 6;
        const float* wp = fc1_w + og * 4;
        float4 acc = {0.f, 0.f, 0.f, 0.f};
#pragma unroll 8
        for (int i = 0; i < 64; ++i) {
            const int k = ks * 64 + i;
            const float mk = m[k];
            const float4 w = *(const float4*)&wp[(size_t)k * 256];
            acc.x += mk * w.x; acc.y += mk * w.y;
            acc.z += mk * w.z; acc.w += mk * w.w;
        }
        red4[t] = acc;
    }
    __syncthreads();
    if (t < 64) {
        float4 a = *(const float4*)&fc1_b[t * 4];
#pragma unroll
        for (int r = 0; r < 16; ++r) {
            const float4 v = red4[r * 64 + t];
            a.x += v.x; a.y += v.y; a.z += v.z; a.w += v.w;
        }
        a.x = lrelu(a.x); a.y = lrelu(a.y); a.z = lrelu(a.z); a.w = lrelu(a.w);
        *(float4*)&h1[t * 4] = a;
    }
    __syncthreads();
    // fc2: 256 -> 128 (leaky)
    {
        const int og = t & 31, ks = t >> 5;
        float4 acc = {0.f, 0.f, 0.f, 0.f};
#pragma unroll
        for (int i = 0; i < 8; ++i) {
            const int k = ks * 8 + i;
            const float hk = h1[k];
            const float4 w = *(const float4*)&fc2_w[k * 128 + og * 4];
            acc.x += hk * w.x; acc.y += hk * w.y;
            acc.z += hk * w.z; acc.w += hk * w.w;
        }
        red4[t] = acc;
    }
    __syncthreads();
    if (t < 32) {
        float4 a = *(const float4*)&fc2_b[t * 4];
#pragma unroll
        for (int r = 0; r < 32; ++r) {
            const float4 v = red4[r * 32 + t];
            a.x += v.x; a.y += v.y; a.z += v.z; a.w += v.w;
        }
        a.x = lrelu(a.x); a.y = lrelu(a.y); a.z = lrelu(a.z); a.w = lrelu(a.w);
        *(float4*)&h2[t * 4] = a;
    }
    __syncthreads();
    // fc3: 128 -> 128 (leaky)
    {
        const int og = t & 31, ks = t >> 5;
        float4 acc = {0.f, 0.f, 0.f, 0.f};
#pragma unroll
        for (int i = 0; i < 4; ++i) {
            const int k = ks * 4 + i;
            const float hk = h2[k];
            const float4 w = *(const float4*)&fc3_w[k * 128 + og * 4];
            acc.x += hk * w.x; acc.y += hk * w.y;
            acc.z += hk * w.z; acc.w += hk * w.w;
        }
        red4[t] = acc;
    }
    __syncthreads();
    if (t < 32) {
        float4 a = *(const float4*)&fc3_b[t * 4];
#pragma unroll
        for (int r = 0; r < 32; ++r) {
            const float4 v = red4[r * 32 + t];
            a.x += v.x; a.y += v.y; a.z += v.z; a.w += v.w;
        }
        a.x = lrelu(a.x); a.y = lrelu(a.y); a.z = lrelu(a.z); a.w = lrelu(a.w);
        *(float4*)&h3[t * 4] = a;
    }
    __syncthreads();
    // bn: 128 -> 32
    {
        const int og = t & 7, ks = t >> 3;
        const float hk = h3[ks];
        const float4 w = *(const float4*)&bn_w[ks * 32 + og * 4];
        float4 acc;
        acc.x = hk * w.x; acc.y = hk * w.y; acc.z = hk * w.z; acc.w = hk * w.w;
        red4[t] = acc;
    }
    __syncthreads();
    if (t < 8) {
        float4 a = *(const float4*)&bn_b[t * 4];
#pragma unroll
        for (int r = 0; r < 128; ++r) {
            const float4 v = red4[r * 8 + t];
            a.x += v.x; a.y += v.y; a.z += v.z; a.w += v.w;
        }
        *(float4*)&z[c * 32 + t * 4] = a;
    }
}

// ---------------------------------------------------------------------------
// K2: theta, grid (107, 8): block owns 256 cols x 8 classes. Weights in regs.
// ---------------------------------------------------------------------------
__global__ __launch_bounds__(256) void theta_kernel(
    const float* __restrict__ z,
    const float* __restrict__ e_w, const float* __restrict__ e_b,
    const float* __restrict__ f_w, const float* __restrict__ f_b,
    float* __restrict__ th_e, float* __restrict__ th_f)
{
    __shared__ __align__(16) float zl[2048];
    const int t = threadIdx.x;
    ((float4*)zl)[t]       = ((const float4*)z)[t];
    ((float4*)zl)[t + 256] = ((const float4*)z)[t + 256];
    __syncthreads();

    int j = blockIdx.x * 256 + t;
    const int cbase = blockIdx.y * 8;
    const float* wbase;
    float* op;
    int stride;
    float bias;
    if (j < 5456) {
        wbase = e_w + j; bias = e_b[j]; op = th_e + j; stride = 5456;
    } else {
        const int jj = j - 5456;
        if (jj >= 21768) return;
        wbase = f_w + jj; bias = f_b[jj]; op = th_f + jj; stride = 21768;
    }
    float wk[32];
#pragma unroll
    for (int k = 0; k < 32; ++k) wk[k] = wbase[(size_t)k * stride];

#pragma unroll
    for (int cc = 0; cc < 8; cc += 4) {
        const int c0 = cbase + cc;
        float a0 = bias, a1 = bias, a2 = bias, a3 = bias;
#pragma unroll
        for (int k4 = 0; k4 < 8; ++k4) {
            const float4 z0 = *(const float4*)&zl[(c0 + 0) * 32 + k4 * 4];
            const float4 z1 = *(const float4*)&zl[(c0 + 1) * 32 + k4 * 4];
            const float4 z2 = *(const float4*)&zl[(c0 + 2) * 32 + k4 * 4];
            const float4 z3 = *(const float4*)&zl[(c0 + 3) * 32 + k4 * 4];
            const float w0 = wk[k4 * 4], w1 = wk[k4 * 4 + 1];
            const float w2 = wk[k4 * 4 + 2], w3 = wk[k4 * 4 + 3];
            a0 += z0.x * w0 + z0.y * w1 + z0.z * w2 + z0.w * w3;
            a1 += z1.x * w0 + z1.y * w1 + z1.z * w2 + z1.w * w3;
            a2 += z2.x * w0 + z2.y * w1 + z2.z * w2 + z2.w * w3;
            a3 += z3.x * w0 + z3.y * w1 + z3.z * w2 + z3.w * w3;
        }
        op[(size_t)(c0 + 0) * stride] = a0;
        op[(size_t)(c0 + 1) * stride] = a1;
        op[(size_t)(c0 + 2) * stride] = a2;
        op[(size_t)(c0 + 3) * stride] = a3;
    }
}

// ---------------------------------------------------------------------------
// K3: func v8. grid (64, 16) = 1024 blocks, 256 thr, 8 batches/pass.
// Weights from GLOBAL (L2/L3-resident theta); LDS = act transposes only.
// LDS layouts: sE[col 0..63][eval 0..15] stride 18; sZ[k 0..31][b 0..7];
// sF/sG[k][b] stride 10; part[kq 0..3][b*8+c8].
// eval vb in [0,16): b = vb&7, sg = vb>>3 (S/G).
// ---------------------------------------------------------------------------
__global__ __launch_bounds__(256, 4) void func_kernel(
    const float* __restrict__ states,
    const float* __restrict__ th_e_all, const float* __restrict__ th_f_all,
    const int* __restrict__ counts, const int* __restrict__ offsets,
    const int* __restrict__ perm, float* __restrict__ out)
{
    __shared__ __align__(16) float sE[64 * SESTR];
    __shared__ __align__(16) float sZ[32 * 8];
    __shared__ __align__(16) float sF[128 * SFSTR];
    __shared__ __align__(16) float sG[128 * SFSTR];
    __shared__ __align__(16) float part[256];

    const int c = blockIdx.x;
    const int s = blockIdx.y;
    const int nb   = counts[c];
    const int base = offsets[c];
    const int chunk = (nb + NSLICE - 1) / NSLICE;
    const int k0 = s * chunk;
    const int k1 = (nb < k0 + chunk) ? nb : (k0 + chunk);
    const int cnt = (k1 > k0) ? (k1 - k0) : 0;
    if (cnt == 0) return;

    const float* te = th_e_all + (size_t)c * 5456;
    const float* tf = th_f_all + (size_t)c * 21768;

    const int t = threadIdx.x;
    // e-L1: lane = (eval vb, col quad cq)
    const int vb   = t & 15;
    const int cq   = (t >> 4) * 4;
    // e-L2: lane = (eval pair vbs2=2a, col pair ce)
    const int vbs2 = (t & 7) * 2;
    const int ce   = (t >> 3) * 2;
    // e-L3: lane = (eval vb, col c3)
    const int c3   = t >> 4;
    // f-L1/L2: lane = (batch pair 2bs, col pair cf)
    const int bs   = t & 3;
    const int cf   = (t >> 2) * 2;
    // f-L3: lane = (b8, c8, k quarter kq)
    const int b8 = t & 7, c8 = (t >> 3) & 7, kq = t >> 6;

    const int passes = (cnt + 7) >> 3;
    for (int p = 0; p < passes; ++p) {
        if (p) __syncthreads();   // prev pass part/sE/sZ reads done

        // states for eval vb: batch slot vb&7, S/G select vb>>3
        const int kk = k0 + p * 8 + (vb & 7);
        const int bi = (kk < k1) ? perm[base + kk] : 0;
        const float2 sv = *(const float2*)&states[(size_t)bi * 4 + (vb >> 3) * 2];

        // ---- e-L1: 2 -> 64 (leaky), w from global ----
        {
            const float4 wa = *(const float4*)&te[cq];
            const float4 wb = *(const float4*)&te[64 + cq];
            const float4 bb = *(const float4*)&te[128 + cq];
            sE[(cq + 0) * SESTR + vb] = lrelu(sv.x * wa.x + sv.y * wb.x + bb.x);
            sE[(cq + 1) * SESTR + vb] = lrelu(sv.x * wa.y + sv.y * wb.y + bb.y);
            sE[(cq + 2) * SESTR + vb] = lrelu(sv.x * wa.z + sv.y * wb.z + bb.z);
            sE[(cq + 3) * SESTR + vb] = lrelu(sv.x * wa.w + sv.y * wb.w + bb.w);
        }
        __syncthreads();

        // ---- e-L2: 64 -> 64 (leaky); 2 evals x 2 cols per thread ----
        float e00, e01, e10, e11;
        {
            float a00 = 0, a01 = 0, a10 = 0, a11 = 0;
#pragma unroll 8
            for (int k = 0; k < 64; ++k) {
                const float2 w = *(const float2*)&te[192 + k * 64 + ce];
                const float2 y = *(const float2*)&sE[k * SESTR + vbs2];
                a00 += y.x * w.x; a01 += y.x * w.y;
                a10 += y.y * w.x; a11 += y.y * w.y;
            }
            const float2 b2 = *(const float2*)&te[4288 + ce];
            e00 = lrelu(a00 + b2.x); e01 = lrelu(a01 + b2.y);
            e10 = lrelu(a10 + b2.x); e11 = lrelu(a11 + b2.y);
        }
        __syncthreads();   // all sE reads done -> overwrite in place
        *(float2*)&sE[(ce + 0) * SESTR + vbs2] = float2{e00, e10};
        *(float2*)&sE[(ce + 1) * SESTR + vbs2] = float2{e01, e11};
        __syncthreads();

        // ---- e-L3: 64 -> 16 (no act) -> zf ----
        {
            float a = 0.f;
#pragma unroll 8
            for (int k = 0; k < 64; ++k)
                a += sE[k * SESTR + vb] * te[4352 + k * 16 + c3];
            a += te[5376 + c3];
            sZ[((vb >> 3) * 16 + c3) * 8 + (vb & 7)] = a;
        }
        __syncthreads();

        // ---- f-L1: 32 -> 128 (leaky); 2 batches x 2 cols ----
        {
            float a00 = 0, a01 = 0, a10 = 0, a11 = 0;
#pragma unroll 8
            for (int k = 0; k < 32; ++k) {
                const float2 w = *(const float2*)&tf[k * 128 + cf];
                const float2 y = *(const float2*)&sZ[k * 8 + bs * 2];
                a00 += y.x * w.x; a01 += y.x * w.y;
                a10 += y.y * w.x; a11 += y.y * w.y;
            }
            const float2 b1 = *(const float2*)&tf[4096 + cf];
            *(float2*)&sF[(cf + 0) * SFSTR + bs * 2] =
                float2{lrelu(a00 + b1.x), lrelu(a10 + b1.x)};
            *(float2*)&sF[(cf + 1) * SFSTR + bs * 2] =
                float2{lrelu(a01 + b1.y), lrelu(a11 + b1.y)};
        }
        __syncthreads();

        // ---- f-L2: 128 -> 128 (leaky) ----
        {
            float a00 = 0, a01 = 0, a10 = 0, a11 = 0;
#pragma unroll 8
            for (int k = 0; k < 128; ++k) {
                const float2 w = *(const float2*)&tf[4224 + k * 128 + cf];
                const float2 y = *(const float2*)&sF[k * SFSTR + bs * 2];
                a00 += y.x * w.x; a01 += y.x * w.y;
                a10 += y.y * w.x; a11 += y.y * w.y;
            }
            const float2 b2 = *(const float2*)&tf[20608 + cf];
            *(float2*)&sG[(cf + 0) * SFSTR + bs * 2] =
                float2{lrelu(a00 + b2.x), lrelu(a10 + b2.x)};
            *(float2*)&sG[(cf + 1) * SFSTR + bs * 2] =
                float2{lrelu(a01 + b2.y), lrelu(a11 + b2.y)};
        }
        __syncthreads();

        // ---- f-L3 partials: 128 -> 8, K-quartered ----
        {
            float a = 0.f;
#pragma unroll 8
            for (int k = kq * 32; k < kq * 32 + 32; ++k)
                a += sG[k * SFSTR + b8] * tf[20736 + k * 8 + c8];
            part[kq * 64 + b8 * 8 + c8] = a;
        }
        __syncthreads();

        // ---- reduce + sin/cos epilogue ----
        if (t < 64) {
            const int bb = t >> 3, cc = t & 7;
            const int kk2 = k0 + p * 8 + bb;
            if (kk2 < k1) {
                const int bi2 = perm[base + kk2];
                const float a = part[bb * 8 + cc] + part[64 + bb * 8 + cc]
                              + part[128 + bb * 8 + cc] + part[192 + bb * 8 + cc]
                              + tf[21760 + cc];
                out[(size_t)bi2 * 16 + cc]     = __sinf(a);
                out[(size_t)bi2 * 16 + 8 + cc] = __cosf(a);
            }
        }
    }
}

// ---------------------------------------------------------------------------
extern "C" void kernel_launch(void* const* d_in, const int* in_sizes, int n_in,
                              void* d_out, int out_size, void* d_ws, size_t ws_size,
                              hipStream_t stream)
{
    const int*   indices = (const int*)  d_in[0];
    const float* states  = (const float*)d_in[1];
    const float* maps    = (const float*)d_in[2];
    const float* fc1_w   = (const float*)d_in[3];
    const float* fc1_b   = (const float*)d_in[4];
    const float* fc2_w   = (const float*)d_in[5];
    const float* fc2_b   = (const float*)d_in[6];
    const float* fc3_w   = (const float*)d_in[7];
    const float* fc3_b   = (const float*)d_in[8];
    const float* bn_w    = (const float*)d_in[9];
    const float* bn_b    = (const float*)d_in[10];
    const float* e_w     = (const float*)d_in[11];
    const float* e_b     = (const float*)d_in[12];
    const float* f_w     = (const float*)d_in[13];
    const float* f_b     = (const float*)d_in[14];
    float* out = (float*)d_out;

    float* ws   = (float*)d_ws;
    float* z    = ws;                    // 2048
    float* th_e = ws + 2048;             // 349184
    float* th_f = ws + 351232;           // 1393152
    int* counts  = (int*)(ws + 1744384); // 64
    int* offsets = counts + 64;          // 64
    int* perm    = counts + 128;         // 8192

    backbone_bucket_kernel<<<65, 1024, 0, stream>>>(
        maps, fc1_w, fc1_b, fc2_w, fc2_b, fc3_w, fc3_b, bn_w, bn_b, z,
        indices, counts, offsets, perm);
    theta_kernel<<<dim3(107, 8), 256, 0, stream>>>(
        z, e_w, e_b, f_w, f_b, th_e, th_f);
    func_kernel<<<dim3(NCLS, NSLICE), 256, 0, stream>>>(
        states, th_e, th_f, counts, offsets, perm, out);
}